// Round 1
// baseline (313.684 us; speedup 1.0000x reference)
//
#include <hip/hip_runtime.h>
#include <hip/hip_bf16.h>
#include <math.h>

typedef __attribute__((ext_vector_type(4))) float f32x4;
typedef __attribute__((ext_vector_type(8))) short short8;
typedef __attribute__((ext_vector_type(4))) short short4v;

#define EDIM 512
#define BM 128
#define BN 128
#define BK 32
#define LDPAD 40  // bf16 elems per LDS row (64B data + 16B pad = 80B, 16B-aligned)

static __device__ __forceinline__ short f2bf(float f) {
  union { float f; unsigned u; } v; v.f = f;
  unsigned r = v.u + 0x7fffu + ((v.u >> 16) & 1u);  // RNE
  return (short)(r >> 16);
}
static __device__ __forceinline__ float bf2f(short s) {
  union { float f; unsigned u; } v; v.u = ((unsigned)(unsigned short)s) << 16;
  return v.f;
}

// ---------------- weight fp32 -> bf16 conversion (tiny) ----------------
__global__ __launch_bounds__(256) void convert_w(
    const float* __restrict__ Wq, const float* __restrict__ Wk, const float* __restrict__ Wv,
    short* __restrict__ Wqb, short* __restrict__ Wkb, short* __restrict__ Wvb) {
  int i = (blockIdx.x * 256 + threadIdx.x) * 4;  // 65536 threads * 4 = 262144
  f32x4 q = *(const f32x4*)(Wq + i);
  f32x4 k = *(const f32x4*)(Wk + i);
  f32x4 v = *(const f32x4*)(Wv + i);
  short4v qs, ks, vs;
#pragma unroll
  for (int j = 0; j < 4; ++j) { qs[j] = f2bf(q[j]); ks[j] = f2bf(k[j]); vs[j] = f2bf(v[j]); }
  *(short4v*)(Wqb + i) = qs;
  *(short4v*)(Wkb + i) = ks;
  *(short4v*)(Wvb + i) = vs;
}

// ---------------- projection GEMM: Y = X @ W^T + b  (bf16 MFMA) ----------------
// grid: (Mc/BM, EDIM/BN, 3)  z: 0=Q(from Xa), 1=K(from Xb), 2=V(from Xb)
__global__ __launch_bounds__(256) void proj_gemm(
    const float* __restrict__ Xa, const float* __restrict__ Xb,
    const short* __restrict__ Wqb, const short* __restrict__ Wkb, const short* __restrict__ Wvb,
    const float* __restrict__ bq, const float* __restrict__ bk, const float* __restrict__ bv,
    short* __restrict__ Qb, short* __restrict__ Kb, short* __restrict__ Vb) {
  __shared__ short Al[BM][LDPAD];
  __shared__ short Bl[BN][LDPAD];

  const int z = blockIdx.z;
  const float* __restrict__ X = (z == 0) ? Xa : Xb;
  const short* __restrict__ W = (z == 0) ? Wqb : (z == 1 ? Wkb : Wvb);
  const float* __restrict__ bias = (z == 0) ? bq : (z == 1 ? bk : bv);
  short* __restrict__ O = (z == 0) ? Qb : (z == 1 ? Kb : Vb);

  const int m0 = blockIdx.x * BM;
  const int n0 = blockIdx.y * BN;
  const int tid = threadIdx.x;
  const int lane = tid & 63;
  const int wv = tid >> 6;
  const int wr = wv >> 1, wc = wv & 1;   // 2x2 wave grid, 64x64 per wave
  const int srow = tid >> 1;             // staging: 2 threads per row
  const int shalf = tid & 1;             // 16 elems each

  const int col = lane & 15;
  const int kg = lane >> 4;

  f32x4 acc[4][4] = {};

  const float* Xrow = X + (size_t)(m0 + srow) * EDIM + shalf * 16;
  const short* Wrow = W + (size_t)(n0 + srow) * EDIM + shalf * 16;

  for (int ks = 0; ks < EDIM / BK; ++ks) {
    const int k0 = ks * BK;
    // global loads (issued before barrier -> overlap previous compute)
    f32x4 a0 = *(const f32x4*)(Xrow + k0);
    f32x4 a1 = *(const f32x4*)(Xrow + k0 + 4);
    f32x4 a2 = *(const f32x4*)(Xrow + k0 + 8);
    f32x4 a3 = *(const f32x4*)(Xrow + k0 + 12);
    short8 b0 = *(const short8*)(Wrow + k0);
    short8 b1 = *(const short8*)(Wrow + k0 + 8);
    short8 av0, av1;
#pragma unroll
    for (int j = 0; j < 4; ++j) {
      av0[j] = f2bf(a0[j]); av0[j + 4] = f2bf(a1[j]);
      av1[j] = f2bf(a2[j]); av1[j + 4] = f2bf(a3[j]);
    }
    __syncthreads();  // previous iter's ds_reads done
    *(short8*)&Al[srow][shalf * 16]     = av0;
    *(short8*)&Al[srow][shalf * 16 + 8] = av1;
    *(short8*)&Bl[srow][shalf * 16]     = b0;
    *(short8*)&Bl[srow][shalf * 16 + 8] = b1;
    __syncthreads();
    short8 af[4], bfv[4];
#pragma unroll
    for (int i = 0; i < 4; ++i)
      af[i] = *(const short8*)&Al[wr * 64 + i * 16 + col][kg * 8];
#pragma unroll
    for (int i = 0; i < 4; ++i)
      bfv[i] = *(const short8*)&Bl[wc * 64 + i * 16 + col][kg * 8];
#pragma unroll
    for (int i = 0; i < 4; ++i)
#pragma unroll
      for (int j = 0; j < 4; ++j)
        acc[i][j] = __builtin_amdgcn_mfma_f32_16x16x32_bf16(af[i], bfv[j], acc[i][j], 0, 0, 0);
  }

  // epilogue: C frag (row=(lane>>4)*4+j, col=lane&15), add bias, store bf16
#pragma unroll
  for (int nj = 0; nj < 4; ++nj) {
    const int e = n0 + wc * 64 + nj * 16 + col;
    const float bb = bias[e];
#pragma unroll
    for (int mi = 0; mi < 4; ++mi) {
      const int mb = m0 + wr * 64 + mi * 16 + kg * 4;
#pragma unroll
      for (int j = 0; j < 4; ++j)
        O[(size_t)(mb + j) * EDIM + e] = f2bf(acc[mi][nj][j] + bb);
    }
  }
}

// ---------------- block attention: one wave per 16-row block ----------------
__global__ __launch_bounds__(256) void attn_kernel(
    const short* __restrict__ Qb, const short* __restrict__ Kb, const short* __restrict__ Vb,
    float* __restrict__ O) {
  __shared__ float plds[4][16][16];
  const int lane = threadIdx.x & 63;
  const int wv = threadIdx.x >> 6;
  const int blk = blockIdx.x * 4 + wv;
  const size_t r0 = (size_t)blk * 16;
  const int col = lane & 15;
  const int kg = lane >> 4;

  // QK^T: A=Q (16x32 slices), B=K (both k-contiguous in memory -> direct frag loads)
  const short* Qp = Qb + (r0 + col) * EDIM + kg * 8;
  const short* Kp = Kb + (r0 + col) * EDIM + kg * 8;
  f32x4 s = {};
#pragma unroll
  for (int ks = 0; ks < 16; ++ks) {
    short8 a = *(const short8*)(Qp + ks * 32);
    short8 b = *(const short8*)(Kp + ks * 32);
    s = __builtin_amdgcn_mfma_f32_16x16x32_bf16(a, b, s, 0, 0, 0);
  }
  const float scale = 0.04419417382415922f;  // 1/sqrt(512)
  float p[4];
#pragma unroll
  for (int j = 0; j < 4; ++j) p[j] = s[j] * scale;
  // row softmax: row lives across lanes (l&15) within each 16-lane group
#pragma unroll
  for (int j = 0; j < 4; ++j) {
    float m = p[j];
#pragma unroll
    for (int d = 1; d < 16; d <<= 1) m = fmaxf(m, __shfl_xor(m, d));
    float e = __expf(p[j] - m);
    float ssum = e;
#pragma unroll
    for (int d = 1; d < 16; d <<= 1) ssum += __shfl_xor(ssum, d);
    p[j] = e / ssum;
  }
#pragma unroll
  for (int j = 0; j < 4; ++j) plds[wv][kg * 4 + j][col] = p[j];
  __syncthreads();

  // PV on VALU: lane owns 8 output columns; V rows read coalesced (1KB/row/wave)
  const int e0 = lane * 8;
  short8 v8[16];
#pragma unroll
  for (int k = 0; k < 16; ++k) v8[k] = *(const short8*)(Vb + (r0 + k) * EDIM + e0);
#pragma unroll
  for (int q = 0; q < 16; ++q) {
    float acc[8] = {0, 0, 0, 0, 0, 0, 0, 0};
#pragma unroll
    for (int k = 0; k < 16; ++k) {
      const float pv = plds[wv][q][k];  // LDS broadcast
#pragma unroll
      for (int i = 0; i < 8; ++i) acc[i] += pv * bf2f(v8[k][i]);
    }
    f32x4 o0 = {acc[0], acc[1], acc[2], acc[3]};
    f32x4 o1 = {acc[4], acc[5], acc[6], acc[7]};
    *(f32x4*)(O + (r0 + q) * EDIM + e0) = o0;
    *(f32x4*)(O + (r0 + q) * EDIM + e0 + 4) = o1;
  }
}

// ---------------- host ----------------
extern "C" void kernel_launch(void* const* d_in, const int* in_sizes, int n_in,
                              void* d_out, int out_size, void* d_ws, size_t ws_size,
                              hipStream_t stream) {
  const float* state1 = (const float*)d_in[0];
  const float* state2 = (const float*)d_in[1];
  const float* Wq = (const float*)d_in[2];
  const float* bq = (const float*)d_in[3];
  const float* Wk = (const float*)d_in[4];
  const float* bk = (const float*)d_in[5];
  const float* Wv = (const float*)d_in[6];
  const float* bv = (const float*)d_in[7];

  const size_t Mtot = (size_t)8 * 4096;  // 32768 rows per state
  float* out1 = (float*)d_out;
  float* out2 = out1 + Mtot * EDIM;

  short* Wqb = (short*)d_ws;
  short* Wkb = Wqb + 262144;
  short* Wvb = Wkb + 262144;
  short* Qbase = Wvb + 262144;

  // chunk the M dimension so 3 bf16 QKV buffers fit in ws
  size_t nch = 1;
  while (nch < 256) {
    size_t need = (3 * 262144 + 3 * (Mtot / nch) * EDIM) * sizeof(short);
    if (need <= ws_size) break;
    nch <<= 1;
  }
  const size_t Mc = Mtot / nch;
  short* Qb = Qbase;
  short* Kb = Qb + Mc * EDIM;
  short* Vb = Kb + Mc * EDIM;

  convert_w<<<dim3(256), dim3(256), 0, stream>>>(Wq, Wk, Wv, Wqb, Wkb, Wvb);

  for (int dir = 0; dir < 2; ++dir) {
    const float* Xa = dir ? state2 : state1;  // Q source
    const float* Xb = dir ? state1 : state2;  // K,V source
    float* Od = dir ? out2 : out1;
    for (size_t c = 0; c < nch; ++c) {
      const size_t roff = c * Mc;
      proj_gemm<<<dim3(Mc / BM, EDIM / BN, 3), dim3(256), 0, stream>>>(
          Xa + roff * EDIM, Xb + roff * EDIM, Wqb, Wkb, Wvb, bq, bk, bv, Qb, Kb, Vb);
      attn_kernel<<<dim3(Mc / 64), dim3(256), 0, stream>>>(Qb, Kb, Vb, Od + roff * EDIM);
    }
  }
}

// Round 2
// 239.518 us; speedup vs baseline: 1.3096x; 1.3096x over previous
//
#include <hip/hip_runtime.h>
#include <hip/hip_bf16.h>

typedef __attribute__((ext_vector_type(4))) float f32x4;
typedef __attribute__((ext_vector_type(8))) short short8;
typedef __attribute__((ext_vector_type(4))) short short4v;

#define EDIM 512
#define BM 128
#define BN 128
#define BK 64
#define WELEMS 262144  // 512*512

static __device__ __forceinline__ short f2bf(float f) {
  union { float f; unsigned u; } v; v.f = f;
  unsigned r = v.u + 0x7fffu + ((v.u >> 16) & 1u);  // RNE
  return (short)(r >> 16);
}
static __device__ __forceinline__ float bf2f(short s) {
  union { float f; unsigned u; } v; v.u = ((unsigned)(unsigned short)s) << 16;
  return v.f;
}

// async global -> LDS, 16B per lane. lds ptr must be wave-uniform base.
static __device__ __forceinline__ void gload_lds16(const short* g, short* l) {
  __builtin_amdgcn_global_load_lds(
      (const __attribute__((address_space(1))) unsigned int*)g,
      (__attribute__((address_space(3))) unsigned int*)(unsigned int)(unsigned long long)l,
      16, 0, 0);
}

// ---------------- weight fp32 -> bf16 (tiny) ----------------
__global__ __launch_bounds__(256) void convert_w(
    const float* __restrict__ Wq, const float* __restrict__ Wk, const float* __restrict__ Wv,
    short* __restrict__ Wb) {
  int i = (blockIdx.x * 256 + threadIdx.x) * 4;
  f32x4 q = *(const f32x4*)(Wq + i);
  f32x4 k = *(const f32x4*)(Wk + i);
  f32x4 v = *(const f32x4*)(Wv + i);
  short4v qs, ks, vs;
#pragma unroll
  for (int j = 0; j < 4; ++j) { qs[j] = f2bf(q[j]); ks[j] = f2bf(k[j]); vs[j] = f2bf(v[j]); }
  *(short4v*)(Wb + i) = qs;
  *(short4v*)(Wb + WELEMS + i) = ks;
  *(short4v*)(Wb + 2 * WELEMS + i) = vs;
}

// ---------------- states fp32 -> bf16 ----------------
__global__ __launch_bounds__(256) void convert_x(
    const float* __restrict__ s1, const float* __restrict__ s2,
    short* __restrict__ o1, short* __restrict__ o2) {
  const long e = ((long)blockIdx.x * 256 + threadIdx.x) * 8;
  f32x4 a0 = *(const f32x4*)(s1 + e), a1 = *(const f32x4*)(s1 + e + 4);
  f32x4 b0 = *(const f32x4*)(s2 + e), b1 = *(const f32x4*)(s2 + e + 4);
  short8 r1, r2;
#pragma unroll
  for (int j = 0; j < 4; ++j) {
    r1[j] = f2bf(a0[j]); r1[j + 4] = f2bf(a1[j]);
    r2[j] = f2bf(b0[j]); r2[j + 4] = f2bf(b1[j]);
  }
  *(short8*)(o1 + e) = r1;
  *(short8*)(o2 + e) = r2;
}

// ---------------- projection GEMM: Y = X @ W^T + b (bf16 MFMA, m97 structure) ----
// grid (Mc/BM, EDIM/BN, 6): z = {q1,k1,v1,q2,k2,v2}; z<3 reads S1b else S2b.
// LDS layout: linear [128 rows][8 chunks of 16B]; global source pre-swizzled with
// chunk ^= (row&7) so swizzled ds_read lands conflict-free (rule #21: both sides).
__global__ __launch_bounds__(256, 3) void proj_gemm(
    const short* __restrict__ S1b, const short* __restrict__ S2b,
    const short* __restrict__ Wb,
    const float* __restrict__ bq, const float* __restrict__ bk, const float* __restrict__ bv,
    short* __restrict__ QKV, size_t Mc) {
  __shared__ short Al[BM * BK];
  __shared__ short Bl[BN * BK];

  const int z = blockIdx.z;
  const short* __restrict__ X = (z < 3) ? S1b : S2b;
  const int wsel = z - (z < 3 ? 0 : 3);
  const short* __restrict__ W = Wb + wsel * WELEMS;
  const float* __restrict__ bias = (wsel == 0) ? bq : (wsel == 1 ? bk : bv);
  short* __restrict__ O = QKV + (size_t)z * Mc * EDIM;

  const int m0 = blockIdx.x * BM;
  const int n0 = blockIdx.y * BN;
  const int tid = threadIdx.x;
  const int lane = tid & 63;
  const int wv = tid >> 6;
  const int wr = wv >> 1, wc = wv & 1;  // 2x2 waves, 64x64 out each
  const int col = lane & 15;
  const int kg = lane >> 4;

  f32x4 acc[4][4] = {};

  for (int ks = 0; ks < EDIM / BK; ++ks) {
    const int k0 = ks * BK;
    __syncthreads();  // prior iter's ds_reads done before overwrite
#pragma unroll
    for (int j = 0; j < 4; ++j) {
      const int g = (j * 4 + wv) * 64 + lane;   // 16B chunk index in tile
      const int row = g >> 3;                   // 8 chunks (128B) per row
      const int sc = (g & 7) ^ (row & 7);       // inverse swizzle on SOURCE
      gload_lds16(X + (size_t)(m0 + row) * EDIM + k0 + sc * 8, Al + (j * 4 + wv) * 512);
      gload_lds16(W + (size_t)(n0 + row) * EDIM + k0 + sc * 8, Bl + (j * 4 + wv) * 512);
    }
    __syncthreads();  // compiler drains vmcnt before barrier
#pragma unroll
    for (int kk = 0; kk < 2; ++kk) {
      short8 af[4], bf8[4];
#pragma unroll
      for (int i = 0; i < 4; ++i) {
        const int ra = wr * 64 + i * 16 + col;
        const int rb = wc * 64 + i * 16 + col;
        af[i]  = *(const short8*)(Al + ra * 64 + ((((kk << 2) + kg) ^ (ra & 7)) << 3));
        bf8[i] = *(const short8*)(Bl + rb * 64 + ((((kk << 2) + kg) ^ (rb & 7)) << 3));
      }
#pragma unroll
      for (int mi = 0; mi < 4; ++mi)
#pragma unroll
        for (int nj = 0; nj < 4; ++nj)
          acc[mi][nj] = __builtin_amdgcn_mfma_f32_16x16x32_bf16(af[mi], bf8[nj], acc[mi][nj], 0, 0, 0);
    }
  }

  // epilogue: C frag row=(lane>>4)*4+j, col=lane&15; add bias; store bf16
#pragma unroll
  for (int nj = 0; nj < 4; ++nj) {
    const int e = n0 + wc * 64 + nj * 16 + col;
    const float bb = bias[e];
#pragma unroll
    for (int mi = 0; mi < 4; ++mi) {
      const size_t mb = m0 + wr * 64 + mi * 16 + kg * 4;
#pragma unroll
      for (int j = 0; j < 4; ++j)
        O[(mb + j) * EDIM + e] = f2bf(acc[mi][nj][j] + bb);
    }
  }
}

// ---------------- block attention: one wave per 16-row block, both dirs ------
__global__ __launch_bounds__(256) void attn_kernel(
    const short* __restrict__ QKV, float* __restrict__ out1, float* __restrict__ out2,
    size_t Mc) {
  __shared__ float plds[4][16][16];
  const int dir = blockIdx.y;
  const size_t sz = Mc * EDIM;
  const short* __restrict__ Q = QKV + (dir ? 3 : 0) * sz;
  const short* __restrict__ K = QKV + (dir ? 1 : 4) * sz;
  const short* __restrict__ V = QKV + (dir ? 2 : 5) * sz;
  float* __restrict__ O = dir ? out2 : out1;

  const int lane = threadIdx.x & 63;
  const int wv = threadIdx.x >> 6;
  const size_t r0 = ((size_t)blockIdx.x * 4 + wv) * 16;
  const int col = lane & 15;
  const int kg = lane >> 4;

  const short* Qp = Q + (r0 + col) * EDIM + kg * 8;
  const short* Kp = K + (r0 + col) * EDIM + kg * 8;
  f32x4 s = {};
#pragma unroll
  for (int ks = 0; ks < 16; ++ks) {
    short8 a = *(const short8*)(Qp + ks * 32);
    short8 b = *(const short8*)(Kp + ks * 32);
    s = __builtin_amdgcn_mfma_f32_16x16x32_bf16(a, b, s, 0, 0, 0);
  }
  const float scale = 0.04419417382415922f;  // 1/sqrt(512)
  float p[4];
#pragma unroll
  for (int j = 0; j < 4; ++j) p[j] = s[j] * scale;
#pragma unroll
  for (int j = 0; j < 4; ++j) {
    float m = p[j];
#pragma unroll
    for (int d = 1; d < 16; d <<= 1) m = fmaxf(m, __shfl_xor(m, d));
    float e = __expf(p[j] - m);
    float ssum = e;
#pragma unroll
    for (int d = 1; d < 16; d <<= 1) ssum += __shfl_xor(ssum, d);
    p[j] = e / ssum;
  }
#pragma unroll
  for (int j = 0; j < 4; ++j) plds[wv][kg * 4 + j][col] = p[j];
  __syncthreads();

  const int e0 = lane * 8;
  short8 v8[16];
#pragma unroll
  for (int k = 0; k < 16; ++k) v8[k] = *(const short8*)(V + (r0 + k) * EDIM + e0);
#pragma unroll
  for (int q = 0; q < 16; ++q) {
    float acc[8] = {0, 0, 0, 0, 0, 0, 0, 0};
#pragma unroll
    for (int k = 0; k < 16; ++k) {
      const float pv = plds[wv][q][k];
#pragma unroll
      for (int i = 0; i < 8; ++i) acc[i] += pv * bf2f(v8[k][i]);
    }
    f32x4 o0 = {acc[0], acc[1], acc[2], acc[3]};
    f32x4 o1 = {acc[4], acc[5], acc[6], acc[7]};
    *(f32x4*)(O + (r0 + q) * EDIM + e0) = o0;
    *(f32x4*)(O + (r0 + q) * EDIM + e0 + 4) = o1;
  }
}

// ---------------- host ----------------
extern "C" void kernel_launch(void* const* d_in, const int* in_sizes, int n_in,
                              void* d_out, int out_size, void* d_ws, size_t ws_size,
                              hipStream_t stream) {
  const float* state1 = (const float*)d_in[0];
  const float* state2 = (const float*)d_in[1];
  const float* Wq = (const float*)d_in[2];
  const float* bq = (const float*)d_in[3];
  const float* Wk = (const float*)d_in[4];
  const float* bk = (const float*)d_in[5];
  const float* Wv = (const float*)d_in[6];
  const float* bv = (const float*)d_in[7];

  const size_t Mtot = (size_t)8 * 4096;
  float* out1 = (float*)d_out;
  float* out2 = out1 + Mtot * EDIM;

  short* Wb = (short*)d_ws;            // 3 * 512*512 bf16 = 1.5 MB
  short* base = Wb + 3 * WELEMS;

  // chunk M so {2 state-chunks + 6 QKV-chunks} bf16 fit in ws
  size_t nch = 1;
  while (nch < 256) {
    size_t need = ((size_t)3 * WELEMS + 8 * (Mtot / nch) * EDIM) * sizeof(short);
    if (need <= ws_size) break;
    nch <<= 1;
  }
  const size_t Mc = Mtot / nch;
  short* S1b = base;
  short* S2b = S1b + Mc * EDIM;
  short* QKV = S2b + Mc * EDIM;  // 6 matrices of Mc x 512

  convert_w<<<dim3(256), dim3(256), 0, stream>>>(Wq, Wk, Wv, Wb);

  for (size_t c = 0; c < nch; ++c) {
    const size_t roff = c * Mc;
    convert_x<<<dim3((unsigned)(Mc / 4)), dim3(256), 0, stream>>>(
        state1 + roff * EDIM, state2 + roff * EDIM, S1b, S2b);
    proj_gemm<<<dim3((unsigned)(Mc / BM), EDIM / BN, 6), dim3(256), 0, stream>>>(
        S1b, S2b, Wb, bq, bk, bv, QKV, Mc);
    attn_kernel<<<dim3((unsigned)(Mc / 64), 2), dim3(256), 0, stream>>>(
        QKV, out1 + roff * EDIM, out2 + roff * EDIM, Mc);
  }
}